// Round 17
// baseline (546.293 us; speedup 1.0000x reference)
//
#include <hip/hip_runtime.h>

#define NN 131072
#define NE 2097152
#define DD 128
#define LL 3

#define NB 256      // partition buckets
#define BSH 9       // log2(nodes per bucket) -> 512 nodes/bucket
#define TILE (NE / NB)   // 8192 edges per pass-A block

typedef __attribute__((ext_vector_type(8))) short short8;
typedef __attribute__((ext_vector_type(4))) float f32x4;

__device__ __forceinline__ ushort f2bf(float f) {
    uint u = __float_as_uint(f);
    return (ushort)((u + 0x7fffu + ((u >> 16) & 1u)) >> 16);   // RNE
}
__device__ __forceinline__ float bflo(uint u) { return __uint_as_float(u << 16); }
__device__ __forceinline__ float bfhi(uint u) { return __uint_as_float(u & 0xffff0000u); }

// ---------------- merged prep: bns zero + weight transpose + x convert ------
__global__ __launch_bounds__(256) void k_prep(const float* __restrict__ x,
                                              const float* __restrict__ Wi,
                                              const float* __restrict__ Wg,
                                              const float* __restrict__ Wr,
                                              uint* __restrict__ xb,
                                              ushort* __restrict__ wt,
                                              float* __restrict__ bns) {
    const int t = threadIdx.x, blk = blockIdx.x;
    const size_t id = (size_t)blk * 256 + t;   // NN*64 dwords
    const int n = (int)(id >> 6);
    const int k0 = (int)(id & 63) * 2;
    float v0 = (k0 < 74) ? x[(size_t)n * 74 + k0] : 0.0f;
    float v1 = (k0 + 1 < 74) ? x[(size_t)n * 74 + k0 + 1] : 0.0f;
    xb[id] = (uint)f2bf(v0) | ((uint)f2bf(v1) << 16);
    if (blk < 448) {
        const int id2 = blk * 256 + t;
        const int m = id2 >> 14;
        const int c = (id2 >> 7) & 127;
        const int k = id2 & 127;
        float v;
        if (m == 0)      v = (k < 74) ? Wi[k * DD + c] : 0.0f;
        else if (m <= 3) v = Wg[(size_t)(m - 1) * DD * DD + k * DD + c];
        else             v = Wr[(size_t)(m - 4) * DD * DD + k * DD + c];
        wt[id2] = f2bf(v);
    }
    if (blk == 448) {
        bns[t] = 0.0f; bns[t + 256] = 0.0f; bns[t + 512] = 0.0f;
    }
}

// ---------------- Pass A: bucket histogram per block ----------------
__global__ __launch_bounds__(256) void kA_count(const int* __restrict__ tgt,
                                                int* __restrict__ blockHist) {
    __shared__ int hist[NB];
    const int t = threadIdx.x, blk = blockIdx.x;
    hist[t] = 0;
    __syncthreads();
    const int base = blk * TILE;
#pragma unroll 8
    for (int j = 0; j < TILE / 256; ++j)
        atomicAdd(&hist[tgt[base + j * 256 + t] >> BSH], 1);
    __syncthreads();
    blockHist[t * NB + blk] = hist[t];   // bucket-major
}

// ---- S1: per-bucket row scan (256 blocks). chunkBase becomes RELATIVE ------
__global__ __launch_bounds__(256) void kA_scan1(int* __restrict__ blockHist,
                                                int* __restrict__ rowSum) {
    __shared__ int sc[256];
    const int t = threadIdx.x, b = blockIdx.x;
    const int v = blockHist[b * NB + t];
    sc[t] = v;
    __syncthreads();
    for (int off = 1; off < 256; off <<= 1) {
        int a = sc[t];
        int u = (t >= off) ? sc[t - off] : 0;
        __syncthreads();
        sc[t] = a + u;
        __syncthreads();
    }
    blockHist[b * NB + t] = sc[t] - v;        // exclusive prefix within row
    if (t == 255) rowSum[b] = sc[255];
}

// ---------------- Pass A scatter (scan2 folded in) ---------------------------
__global__ __launch_bounds__(256) void kA_scatter(const int* __restrict__ src,
                                                  const int* __restrict__ tgt,
                                                  const int* __restrict__ chunkBase,
                                                  const int* __restrict__ rowSum,
                                                  int* __restrict__ bstart,
                                                  uint* __restrict__ packed) {
    __shared__ int cur[NB];
    __shared__ int sc[256];
    const int t = threadIdx.x, blk = blockIdx.x;
    const int v = rowSum[t];
    sc[t] = v;
    __syncthreads();
    for (int off = 1; off < 256; off <<= 1) {
        int a = sc[t];
        int u = (t >= off) ? sc[t - off] : 0;
        __syncthreads();
        sc[t] = a + u;
        __syncthreads();
    }
    const int bst = sc[t] - v;                 // exclusive bucket start
    cur[t] = bst + chunkBase[t * NB + blk];
    if (blk == 0) {
        bstart[t] = bst;
        if (t == 255) bstart[NB] = sc[255];
    }
    __syncthreads();
    const int base = blk * TILE;
#pragma unroll 4
    for (int j = 0; j < TILE / 256; ++j) {
        const int e = base + j * 256 + t;
        const int tg = tgt[e], s = src[e];
        const int b = tg >> BSH;
        const int pos = atomicAdd(&cur[b], 1);
        packed[pos] = (uint)s | ((uint)(tg & ((1 << BSH) - 1)) << 17);
    }
}

// ------ Pass B: per-bucket counting sort -> rowp, dinv, deg, ssrc ------------
__global__ __launch_bounds__(256) void kB_sort(const uint* __restrict__ packed,
                                               const int* __restrict__ bstart,
                                               int* __restrict__ rowp,
                                               float* __restrict__ dinv,
                                               int* __restrict__ deg,
                                               int* __restrict__ ssrc) {
    __shared__ int cnt[1 << BSH];
    __shared__ int pscan[256];
    const int t = threadIdx.x, b = blockIdx.x;
    const int e0 = bstart[b], e1 = bstart[b + 1];
    cnt[t] = 0; cnt[t + 256] = 0;
    __syncthreads();
    for (int e = e0 + t; e < e1; e += 256)
        atomicAdd(&cnt[packed[e] >> 17], 1);
    __syncthreads();
    const int c0 = cnt[2 * t], c1 = cnt[2 * t + 1];
    pscan[t] = c0 + c1;
    __syncthreads();
    for (int off = 1; off < 256; off <<= 1) {
        int v = pscan[t];
        int u = (t >= off) ? pscan[t - off] : 0;
        __syncthreads();
        pscan[t] = v + u;
        __syncthreads();
    }
    const int ex0 = pscan[t] - c0 - c1;
    const int ex1 = ex0 + c0;
    const int n0 = (b << BSH) + 2 * t;
    rowp[n0] = e0 + ex0;
    rowp[n0 + 1] = e0 + ex1;
    dinv[n0] = rsqrtf((float)(c0 + 1));
    dinv[n0 + 1] = rsqrtf((float)(c1 + 1));
    deg[n0] = c0 + 1;
    deg[n0 + 1] = c1 + 1;
    if (b == NB - 1 && t == 255) rowp[NN] = e1;
    __syncthreads();
    cnt[2 * t] = ex0;
    cnt[2 * t + 1] = ex1;
    __syncthreads();
    for (int e = e0 + t; e < e1; e += 256) {
        const uint p = packed[e];
        const int tl = p >> 17;
        const int pos = atomicAdd(&cnt[tl], 1);
        ssrc[e0 + pos] = (int)(p & 0x1FFFFu);
    }
}

// -------- pack source degree: ssrc[e] = s | (deg[s]<<17)  (deg+1 < 2^15) -----
__global__ __launch_bounds__(256) void k_pack(int* __restrict__ ssrc,
                                              const int* __restrict__ deg) {
    const int e = blockIdx.x * 256 + threadIdx.x;
    const int s = ssrc[e];
    ssrc[e] = s | (deg[s] << 17);
}

// ---------------- MFMA GEMM: [N,128] @ Wt^T  (r16 multi-tile pipelined) ------
// MODE 0: outb = bf16(acc)                                   (init transform)
// MODE 2: outb = bf16(relu(conv*sc+sh) + acc + bres), sc/sh from bnsums
// MODE 3: outf = relu(conv*sc+sh) + acc + bres (f32 final output only)
#define STAGE_A(buf, rowbase)                                                  \
    for (int ch = w * 4; ch < w * 4 + 4; ++ch) {                               \
        const int row_ = ch * 4 + lr;                                          \
        const int kb_ = (lc * 16) ^ ((row_ & 7) << 4);                         \
        const ushort* srcA_ = A + ((rowbase) + row_) * DD + (kb_ >> 1);        \
        __builtin_amdgcn_global_load_lds(                                      \
            (const __attribute__((address_space(1))) void*)srcA_,              \
            (__attribute__((address_space(3))) void*)(As[buf] + ch * 512),     \
            16, 0, 0);                                                         \
    }

template <int MODE>
__global__ __launch_bounds__(256) void k_mgemm(const ushort* __restrict__ A,
                                               const ushort* __restrict__ Bt,
                                               ushort* outb,
                                               float* __restrict__ outf,
                                               const ushort* __restrict__ convb,
                                               const float* __restrict__ gamma,
                                               const float* __restrict__ beta,
                                               const float* __restrict__ bres,
                                               float* __restrict__ bnsums) {
    __shared__ ushort Bs[16384];      // 128 cols x 128 k, XOR-swizzled, 32KB
    __shared__ ushort As[2][8192];    // 2 x (64 rows x 128 k), 2x16KB
    __shared__ float sred[256];
    const int t = threadIdx.x;
    const int w = t >> 6, l = t & 63;
    const int lc = l & 15, lr = l >> 4;
    const size_t base0 = (size_t)blockIdx.x * 256;   // 4 tiles x 64 rows

    for (int ch = w * 8; ch < w * 8 + 8; ++ch) {
        const int row = ch * 4 + lr;
        const int kb = (lc * 16) ^ ((row & 7) << 4);
        const ushort* srcB = Bt + (size_t)row * DD + (kb >> 1);
        __builtin_amdgcn_global_load_lds(
            (const __attribute__((address_space(1))) void*)srcB,
            (__attribute__((address_space(3))) void*)(Bs + ch * 512), 16, 0, 0);
    }
    STAGE_A(0, base0);
    if (MODE >= 2 && t < DD) {          // folded BN-finalize
        const float invN = 1.0f / (float)NN;
        const float mean = bnsums[t] * invN;
        const float var = bnsums[DD + t] * invN - mean * mean;
        const float sc = gamma[t] * rsqrtf(var + 1e-5f);
        sred[t] = sc;
        sred[DD + t] = beta[t] - mean * sc;
    }
    __syncthreads();

    float scv[8], shv[8], bbv[8];
    if (MODE >= 2) {
#pragma unroll
        for (int n = 0; n < 8; ++n) {
            const int c = n * 16 + lc;
            scv[n] = sred[c]; shv[n] = sred[DD + c]; bbv[n] = bres[c];
        }
    }

    int cur = 0;
    for (int tt = 0; tt < 4; ++tt) {
        const size_t row0 = base0 + tt * 64;
        if (tt < 3) STAGE_A(cur ^ 1, row0 + 64);   // issue BEFORE compute

        f32x4 acc[8] = {};
        const char* Ab = (const char*)As[cur];
        const char* Bb = (const char*)Bs;
#pragma unroll
        for (int kk = 0; kk < 4; ++kk) {
            const int kb = kk * 64 + lr * 16;
            const int r = w * 16 + lc;
            const short8 a = *(const short8*)(Ab + r * 256 + (kb ^ ((r & 7) << 4)));
#pragma unroll
            for (int n = 0; n < 8; ++n) {
                const int c = n * 16 + lc;
                short8 b = *(const short8*)(Bb + c * 256 + (kb ^ ((c & 7) << 4)));
                acc[n] = __builtin_amdgcn_mfma_f32_16x16x32_bf16(a, b, acc[n], 0, 0, 0);
            }
        }

        if (MODE == 0) {
#pragma unroll
            for (int n = 0; n < 8; ++n) {
                const int c = n * 16 + lc;
#pragma unroll
                for (int j = 0; j < 4; ++j) {
                    const size_t r = row0 + w * 16 + lr * 4 + j;
                    outb[r * DD + c] = f2bf(acc[n][j]);
                }
            }
        } else {
#pragma unroll
            for (int n = 0; n < 8; ++n) {
                const int c = n * 16 + lc;
#pragma unroll
                for (int j = 0; j < 4; ++j) {
                    const size_t r = row0 + w * 16 + lr * 4 + j;
                    const float cv = __uint_as_float((uint)convb[r * DD + c] << 16);
                    const float v = fmaxf(cv * scv[n] + shv[n], 0.0f) + acc[n][j] + bbv[n];
                    if (MODE == 2) outb[r * DD + c] = f2bf(v);
                    if (MODE == 3) outf[r * DD + c] = v;
                }
            }
        }
        __syncthreads();    // drains next-tile stage (issued pre-compute)
        cur ^= 1;
    }
}

// ------- FUSED aggregate + GCN GEMM: conv = bf16(Agg(hb)) @ Wg + BN sums -----
// 512 threads / 8 waves per block; block owns 64 nodes. Each wave aggregates
// 8 nodes (r13 LDS-broadcast inner loop, unchanged) writing bf16 results into
// a swizzled LDS A-tile via ds_write; one barrier; 64x128 MFMA vs Wg (staged
// at entry, drained by the same barrier); epilogue writes convb + BN sums.
__global__ __launch_bounds__(512) void k_aggemm(const int* __restrict__ rowp,
                                                const float* __restrict__ dinv,
                                                const int* __restrict__ ssrc,
                                                const uint* __restrict__ hb,
                                                const ushort* __restrict__ Bt,
                                                ushort* __restrict__ convb,
                                                float* __restrict__ bnsums) {
    __shared__ ushort Ag[8192];    // 64 rows x 128 k, XOR-swizzled, 16KB
    __shared__ ushort Bs[16384];   // Wg, 32KB
    __shared__ float2 eb[8][64];   // per-wave edge broadcast slots, 4KB
    __shared__ float sred[256];
    const int t = threadIdx.x;
    const int w = t >> 6, l = t & 63;
    const int lc = l & 15, lr = l >> 4;
    const int base0 = blockIdx.x * 64;

    // stage Wg (32 chunks, 4 per wave) — overlaps the whole aggregate phase
    for (int ch = w * 4; ch < w * 4 + 4; ++ch) {
        const int row = ch * 4 + lr;
        const int kb = (lc * 16) ^ ((row & 7) << 4);
        const ushort* srcB = Bt + (size_t)row * DD + (kb >> 1);
        __builtin_amdgcn_global_load_lds(
            (const __attribute__((address_space(1))) void*)srcB,
            (__attribute__((address_space(3))) void*)(Bs + ch * 512), 16, 0, 0);
    }
    if (t < 256) sred[t] = 0.0f;

    // aggregate 8 nodes per wave into the swizzled LDS A-tile
    for (int ni = 0; ni < 8; ++ni) {
        const int nl = w * 8 + ni;            // local row 0..63
        const int n = base0 + nl;
        const float dn = dinv[n];
        const uint u0 = hb[((uint)n << 6) + l];
        const float dn2 = dn * dn;
        float ax = dn2 * bflo(u0), ay = dn2 * bfhi(u0);
        const int e0 = rowp[n], e1 = rowp[n + 1];
        for (int base = e0; base < e1; base += 64) {
            const int cnt = min(64, e1 - base);
            float nm = 0.0f; uint sb = 0;
            if (l < cnt) {
                const uint p = (uint)__builtin_nontemporal_load(ssrc + base + l);
                sb = (p & 0x1FFFFu) << 6;
                nm = dn * rsqrtf((float)(p >> 17));   // = dn * dinv[src]
            }
            eb[w][l] = make_float2(nm, __uint_as_float(sb));
            int i = 0;
            for (; i + 16 <= cnt; i += 16) {
                uint vv[16]; float nmv[16];
#pragma unroll
                for (int j = 0; j < 16; ++j) {
                    const float2 e = eb[w][i + j];
                    nmv[j] = e.x;
                    vv[j] = hb[__float_as_uint(e.y) + l];
                }
#pragma unroll
                for (int j = 0; j < 16; ++j) {
                    ax += nmv[j] * bflo(vv[j]);
                    ay += nmv[j] * bfhi(vv[j]);
                }
            }
            for (; i < cnt; i += 8) {
                uint vv[8]; float nmv[8];
#pragma unroll
                for (int j = 0; j < 8; ++j) {
                    const float2 e = eb[w][i + j];
                    nmv[j] = e.x;
                    vv[j] = hb[__float_as_uint(e.y) + l];
                }
#pragma unroll
                for (int j = 0; j < 8; ++j) {
                    ax += nmv[j] * bflo(vv[j]);
                    ay += nmv[j] * bfhi(vv[j]);
                }
            }
        }
        const uint ov = (uint)f2bf(ax) | ((uint)f2bf(ay) << 16);
        // lane l holds k-bytes 4l..4l+3 of row nl; swizzle XOR hits bits 4-6
        *(uint*)((char*)Ag + nl * 256 + ((4 * l) ^ ((nl & 7) << 4))) = ov;
    }
    __syncthreads();   // drains ds_writes (Ag) + global_load_lds (Bs)

    // MFMA: wave w computes rows (w&3)*16..+16, cols (w>>2)*64..+64
    f32x4 acc[4] = {};
    const char* Ab = (const char*)Ag;
    const char* Bb = (const char*)Bs;
    const int rg = (w & 3) * 16;
    const int cg = (w >> 2) * 64;
#pragma unroll
    for (int kk = 0; kk < 4; ++kk) {
        const int kb = kk * 64 + lr * 16;
        const int r = rg + lc;
        const short8 a = *(const short8*)(Ab + r * 256 + (kb ^ ((r & 7) << 4)));
#pragma unroll
        for (int n2 = 0; n2 < 4; ++n2) {
            const int c = cg + n2 * 16 + lc;
            short8 b = *(const short8*)(Bb + c * 256 + (kb ^ ((c & 7) << 4)));
            acc[n2] = __builtin_amdgcn_mfma_f32_16x16x32_bf16(a, b, acc[n2], 0, 0, 0);
        }
    }

    // epilogue: convb (bf16) + column sum/sumsq
#pragma unroll
    for (int n2 = 0; n2 < 4; ++n2) {
        const int c = cg + n2 * 16 + lc;
        float ps = 0.0f, ps2 = 0.0f;
#pragma unroll
        for (int j = 0; j < 4; ++j) {
            const size_t r = (size_t)base0 + rg + lr * 4 + j;
            const float v = acc[n2][j];
            convb[r * DD + c] = f2bf(v);
            ps += v; ps2 += v * v;
        }
        atomicAdd(&sred[c], ps);
        atomicAdd(&sred[DD + c], ps2);
    }
    __syncthreads();
    if (t < 256) atomicAdd(&bnsums[t], sred[t]);
}

// ---------------- launch ----------------
extern "C" void kernel_launch(void* const* d_in, const int* in_sizes, int n_in,
                              void* d_out, int out_size, void* d_ws, size_t ws_size,
                              hipStream_t stream) {
    const float* x      = (const float*)d_in[0];
    const int*   ei     = (const int*)d_in[1];
    const float* W_init = (const float*)d_in[3];
    const float* W_gcn  = (const float*)d_in[4];
    const float* gamma  = (const float*)d_in[6];
    const float* beta   = (const float*)d_in[7];
    const float* W_res  = (const float*)d_in[8];
    const float* b_res  = (const float*)d_in[9];

    float* h = (float*)d_out;
    char* p = (char*)d_ws;
    ushort* hb   = (ushort*)p;           p += (size_t)NN * DD * 2;   // 32MB
    ushort* convb = (ushort*)p;          p += (size_t)NN * DD * 2;   // 32MB
    uint*   xb   = (uint*)convb;         // aliases convb: dead before conv write
    float*  dinv = (float*)p;            p += (size_t)NN * 4;
    int*    deg  = (int*)p;              p += (size_t)NN * 4;
    float*  bns  = (float*)p;            p += 768 * 4;
    ushort* wt   = (ushort*)p;           p += 7 * 16384 * 2;
    int* blockHist = (int*)p;            p += (size_t)NB * NB * 4;
    int* rowSum  = (int*)p;              p += NB * 4;
    int* bstart  = (int*)p;              p += (NB + 1) * 4 + 4;
    uint* packed = (uint*)p;             p += (size_t)NE * 4;
    int* rowp    = (int*)p;              p += ((size_t)NN + 1) * 4 + 4;
    int* ssrc    = (int*)p;

    const int* srcp = ei;
    const int* tgtp = ei + NE;

    k_prep<<<NN * 64 / 256, 256, 0, stream>>>(x, W_init, W_gcn, W_res, xb, wt, bns);
    kA_count<<<NB, 256, 0, stream>>>(tgtp, blockHist);
    kA_scan1<<<NB, 256, 0, stream>>>(blockHist, rowSum);
    kA_scatter<<<NB, 256, 0, stream>>>(srcp, tgtp, blockHist, rowSum, bstart, packed);
    kB_sort<<<NB, 256, 0, stream>>>(packed, bstart, rowp, dinv, deg, ssrc);
    k_pack<<<NE / 256, 256, 0, stream>>>(ssrc, deg);

    k_mgemm<0><<<NN / 256, 256, 0, stream>>>((const ushort*)xb, wt, hb,
                                             nullptr, nullptr, nullptr, nullptr,
                                             nullptr, nullptr);

    for (int i = 0; i < LL; ++i) {
        k_aggemm<<<NN / 64, 512, 0, stream>>>(rowp, dinv, ssrc, (const uint*)hb,
                                              wt + (size_t)(1 + i) * 16384,
                                              convb, bns + i * 256);
        if (i < LL - 1)
            k_mgemm<2><<<NN / 256, 256, 0, stream>>>(hb, wt + (size_t)(4 + i) * 16384,
                                                     hb, nullptr, convb,
                                                     gamma + i * DD, beta + i * DD,
                                                     b_res + i * DD, bns + i * 256);
        else
            k_mgemm<3><<<NN / 256, 256, 0, stream>>>(hb, wt + (size_t)(4 + i) * 16384,
                                                     nullptr, h, convb,
                                                     gamma + i * DD, beta + i * DD,
                                                     b_res + i * DD, bns + i * 256);
    }
}

// Round 18
// 471.529 us; speedup vs baseline: 1.1586x; 1.1586x over previous
//
#include <hip/hip_runtime.h>

#define NN 131072
#define NE 2097152
#define DD 128
#define LL 3

#define NB 256      // partition buckets
#define BSH 9       // log2(nodes per bucket) -> 512 nodes/bucket
#define TILE (NE / NB)   // 8192 edges per pass-A block

typedef __attribute__((ext_vector_type(8))) short short8;
typedef __attribute__((ext_vector_type(4))) float f32x4;

__device__ __forceinline__ ushort f2bf(float f) {
    uint u = __float_as_uint(f);
    return (ushort)((u + 0x7fffu + ((u >> 16) & 1u)) >> 16);   // RNE
}
__device__ __forceinline__ float bflo(uint u) { return __uint_as_float(u << 16); }
__device__ __forceinline__ float bfhi(uint u) { return __uint_as_float(u & 0xffff0000u); }

// ---------------- merged prep: bns zero + weight transpose + x convert ------
__global__ __launch_bounds__(256) void k_prep(const float* __restrict__ x,
                                              const float* __restrict__ Wi,
                                              const float* __restrict__ Wg,
                                              const float* __restrict__ Wr,
                                              uint* __restrict__ xb,
                                              ushort* __restrict__ wt,
                                              float* __restrict__ bns) {
    const int t = threadIdx.x, blk = blockIdx.x;
    const size_t id = (size_t)blk * 256 + t;   // NN*64 dwords
    const int n = (int)(id >> 6);
    const int k0 = (int)(id & 63) * 2;
    float v0 = (k0 < 74) ? x[(size_t)n * 74 + k0] : 0.0f;
    float v1 = (k0 + 1 < 74) ? x[(size_t)n * 74 + k0 + 1] : 0.0f;
    xb[id] = (uint)f2bf(v0) | ((uint)f2bf(v1) << 16);
    if (blk < 448) {
        const int id2 = blk * 256 + t;
        const int m = id2 >> 14;
        const int c = (id2 >> 7) & 127;
        const int k = id2 & 127;
        float v;
        if (m == 0)      v = (k < 74) ? Wi[k * DD + c] : 0.0f;
        else if (m <= 3) v = Wg[(size_t)(m - 1) * DD * DD + k * DD + c];
        else             v = Wr[(size_t)(m - 4) * DD * DD + k * DD + c];
        wt[id2] = f2bf(v);
    }
    if (blk == 448) {
        bns[t] = 0.0f; bns[t + 256] = 0.0f; bns[t + 512] = 0.0f;
    }
}

// ---------------- Pass A: bucket histogram per block ----------------
__global__ __launch_bounds__(256) void kA_count(const int* __restrict__ tgt,
                                                int* __restrict__ blockHist) {
    __shared__ int hist[NB];
    const int t = threadIdx.x, blk = blockIdx.x;
    hist[t] = 0;
    __syncthreads();
    const int base = blk * TILE;
#pragma unroll 8
    for (int j = 0; j < TILE / 256; ++j)
        atomicAdd(&hist[tgt[base + j * 256 + t] >> BSH], 1);
    __syncthreads();
    blockHist[t * NB + blk] = hist[t];   // bucket-major
}

// ---- S1: per-bucket row scan (256 blocks). chunkBase becomes RELATIVE ------
__global__ __launch_bounds__(256) void kA_scan1(int* __restrict__ blockHist,
                                                int* __restrict__ rowSum) {
    __shared__ int sc[256];
    const int t = threadIdx.x, b = blockIdx.x;
    const int v = blockHist[b * NB + t];
    sc[t] = v;
    __syncthreads();
    for (int off = 1; off < 256; off <<= 1) {
        int a = sc[t];
        int u = (t >= off) ? sc[t - off] : 0;
        __syncthreads();
        sc[t] = a + u;
        __syncthreads();
    }
    blockHist[b * NB + t] = sc[t] - v;        // exclusive prefix within row
    if (t == 255) rowSum[b] = sc[255];
}

// ---------------- Pass A scatter (scan2 folded in) ---------------------------
__global__ __launch_bounds__(256) void kA_scatter(const int* __restrict__ src,
                                                  const int* __restrict__ tgt,
                                                  const int* __restrict__ chunkBase,
                                                  const int* __restrict__ rowSum,
                                                  int* __restrict__ bstart,
                                                  uint* __restrict__ packed) {
    __shared__ int cur[NB];
    __shared__ int sc[256];
    const int t = threadIdx.x, blk = blockIdx.x;
    const int v = rowSum[t];
    sc[t] = v;
    __syncthreads();
    for (int off = 1; off < 256; off <<= 1) {
        int a = sc[t];
        int u = (t >= off) ? sc[t - off] : 0;
        __syncthreads();
        sc[t] = a + u;
        __syncthreads();
    }
    const int bst = sc[t] - v;                 // exclusive bucket start
    cur[t] = bst + chunkBase[t * NB + blk];
    if (blk == 0) {
        bstart[t] = bst;
        if (t == 255) bstart[NB] = sc[255];
    }
    __syncthreads();
    const int base = blk * TILE;
#pragma unroll 4
    for (int j = 0; j < TILE / 256; ++j) {
        const int e = base + j * 256 + t;
        const int tg = tgt[e], s = src[e];
        const int b = tg >> BSH;
        const int pos = atomicAdd(&cur[b], 1);
        packed[pos] = (uint)s | ((uint)(tg & ((1 << BSH) - 1)) << 17);
    }
}

// ------ Pass B: per-bucket counting sort -> rowp, dinv, deg, ssrc ------------
__global__ __launch_bounds__(256) void kB_sort(const uint* __restrict__ packed,
                                               const int* __restrict__ bstart,
                                               int* __restrict__ rowp,
                                               float* __restrict__ dinv,
                                               int* __restrict__ deg,
                                               int* __restrict__ ssrc) {
    __shared__ int cnt[1 << BSH];
    __shared__ int pscan[256];
    const int t = threadIdx.x, b = blockIdx.x;
    const int e0 = bstart[b], e1 = bstart[b + 1];
    cnt[t] = 0; cnt[t + 256] = 0;
    __syncthreads();
    for (int e = e0 + t; e < e1; e += 256)
        atomicAdd(&cnt[packed[e] >> 17], 1);
    __syncthreads();
    const int c0 = cnt[2 * t], c1 = cnt[2 * t + 1];
    pscan[t] = c0 + c1;
    __syncthreads();
    for (int off = 1; off < 256; off <<= 1) {
        int v = pscan[t];
        int u = (t >= off) ? pscan[t - off] : 0;
        __syncthreads();
        pscan[t] = v + u;
        __syncthreads();
    }
    const int ex0 = pscan[t] - c0 - c1;
    const int ex1 = ex0 + c0;
    const int n0 = (b << BSH) + 2 * t;
    rowp[n0] = e0 + ex0;
    rowp[n0 + 1] = e0 + ex1;
    dinv[n0] = rsqrtf((float)(c0 + 1));
    dinv[n0 + 1] = rsqrtf((float)(c1 + 1));
    deg[n0] = c0 + 1;
    deg[n0 + 1] = c1 + 1;
    if (b == NB - 1 && t == 255) rowp[NN] = e1;
    __syncthreads();
    cnt[2 * t] = ex0;
    cnt[2 * t + 1] = ex1;
    __syncthreads();
    for (int e = e0 + t; e < e1; e += 256) {
        const uint p = packed[e];
        const int tl = p >> 17;
        const int pos = atomicAdd(&cnt[tl], 1);
        ssrc[e0 + pos] = (int)(p & 0x1FFFFu);
    }
}

// -------- pack source degree: ssrc[e] = s | (deg[s]<<17)  (deg+1 < 2^15) -----
__global__ __launch_bounds__(256) void k_pack(int* __restrict__ ssrc,
                                              const int* __restrict__ deg) {
    const int e = blockIdx.x * 256 + threadIdx.x;
    const int s = ssrc[e];
    ssrc[e] = s | (deg[s] << 17);
}

// ---------------- MFMA GEMM: [N,128] @ Wt^T  -------------------------------
// Multi-tile pipelined: each block owns 4 consecutive 64-row tiles.
// B (32KB) staged ONCE; A double-buffered (2x16KB): next-tile stage is issued
// BEFORE the current tile's compute, so the barrier's vmcnt(0) drains loads
// that flew under ds_read+MFMA+epilogue (T3 minimum 2-phase, plain HIP).
// MODE 0: outb = bf16(acc)                                   (init transform)
// MODE 1: outb = bf16(acc) (conv) + column sum/sumsq(f32) -> bnsums (GCN gemm)
// MODE 2: outb = bf16(relu(conv*sc+sh) + acc + bres), sc/sh from bnsums
// MODE 3: outf = relu(conv*sc+sh) + acc + bres (f32 final output only)
#define STAGE_A(buf, rowbase)                                                  \
    for (int ch = w * 4; ch < w * 4 + 4; ++ch) {                               \
        const int row_ = ch * 4 + lr;                                          \
        const int kb_ = (lc * 16) ^ ((row_ & 7) << 4);                         \
        const ushort* srcA_ = A + ((rowbase) + row_) * DD + (kb_ >> 1);        \
        __builtin_amdgcn_global_load_lds(                                      \
            (const __attribute__((address_space(1))) void*)srcA_,              \
            (__attribute__((address_space(3))) void*)(As[buf] + ch * 512),     \
            16, 0, 0);                                                         \
    }

template <int MODE>
__global__ __launch_bounds__(256) void k_mgemm(const ushort* __restrict__ A,
                                               const ushort* __restrict__ Bt,
                                               ushort* outb,
                                               float* __restrict__ outf,
                                               const ushort* __restrict__ convb,
                                               const float* __restrict__ gamma,
                                               const float* __restrict__ beta,
                                               const float* __restrict__ bres,
                                               float* __restrict__ bnsums) {
    __shared__ ushort Bs[16384];      // 128 cols x 128 k, XOR-swizzled, 32KB
    __shared__ ushort As[2][8192];    // 2 x (64 rows x 128 k), 2x16KB
    __shared__ float sred[256];
    const int t = threadIdx.x;
    const int w = t >> 6, l = t & 63;
    const int lc = l & 15, lr = l >> 4;
    const size_t base0 = (size_t)blockIdx.x * 256;   // 4 tiles x 64 rows

    // stage B once (32 chunks, 8 per wave)
    for (int ch = w * 8; ch < w * 8 + 8; ++ch) {
        const int row = ch * 4 + lr;
        const int kb = (lc * 16) ^ ((row & 7) << 4);
        const ushort* srcB = Bt + (size_t)row * DD + (kb >> 1);
        __builtin_amdgcn_global_load_lds(
            (const __attribute__((address_space(1))) void*)srcB,
            (__attribute__((address_space(3))) void*)(Bs + ch * 512), 16, 0, 0);
    }
    STAGE_A(0, base0);
    if (MODE >= 2 && t < DD) {          // folded BN-finalize
        const float invN = 1.0f / (float)NN;
        const float mean = bnsums[t] * invN;
        const float var = bnsums[DD + t] * invN - mean * mean;
        const float sc = gamma[t] * rsqrtf(var + 1e-5f);
        sred[t] = sc;
        sred[DD + t] = beta[t] - mean * sc;
    }
    __syncthreads();

    float scv[8], shv[8], bbv[8];
    if (MODE >= 2) {
#pragma unroll
        for (int n = 0; n < 8; ++n) {
            const int c = n * 16 + lc;
            scv[n] = sred[c]; shv[n] = sred[DD + c]; bbv[n] = bres[c];
        }
    }
    float ps[8] = {}, ps2[8] = {};      // MODE1 cross-tile column sums

    int cur = 0;
    for (int tt = 0; tt < 4; ++tt) {
        const size_t row0 = base0 + tt * 64;
        if (tt < 3) STAGE_A(cur ^ 1, row0 + 64);   // issue BEFORE compute

        f32x4 acc[8] = {};
        const char* Ab = (const char*)As[cur];
        const char* Bb = (const char*)Bs;
#pragma unroll
        for (int kk = 0; kk < 4; ++kk) {
            const int kb = kk * 64 + lr * 16;
            const int r = w * 16 + lc;
            const short8 a = *(const short8*)(Ab + r * 256 + (kb ^ ((r & 7) << 4)));
#pragma unroll
            for (int n = 0; n < 8; ++n) {
                const int c = n * 16 + lc;
                short8 b = *(const short8*)(Bb + c * 256 + (kb ^ ((c & 7) << 4)));
                acc[n] = __builtin_amdgcn_mfma_f32_16x16x32_bf16(a, b, acc[n], 0, 0, 0);
            }
        }

        if (MODE == 0) {
#pragma unroll
            for (int n = 0; n < 8; ++n) {
                const int c = n * 16 + lc;
#pragma unroll
                for (int j = 0; j < 4; ++j) {
                    const size_t r = row0 + w * 16 + lr * 4 + j;
                    outb[r * DD + c] = f2bf(acc[n][j]);
                }
            }
        } else if (MODE == 1) {
#pragma unroll
            for (int n = 0; n < 8; ++n) {
                const int c = n * 16 + lc;
#pragma unroll
                for (int j = 0; j < 4; ++j) {
                    const size_t r = row0 + w * 16 + lr * 4 + j;
                    const float v = acc[n][j];
                    outb[r * DD + c] = f2bf(v);
                    ps[n] += v; ps2[n] += v * v;
                }
            }
        } else {
#pragma unroll
            for (int n = 0; n < 8; ++n) {
                const int c = n * 16 + lc;
#pragma unroll
                for (int j = 0; j < 4; ++j) {
                    const size_t r = row0 + w * 16 + lr * 4 + j;
                    const float cv = __uint_as_float((uint)convb[r * DD + c] << 16);
                    const float v = fmaxf(cv * scv[n] + shv[n], 0.0f) + acc[n][j] + bbv[n];
                    if (MODE == 2) outb[r * DD + c] = f2bf(v);
                    if (MODE == 3) outf[r * DD + c] = v;
                }
            }
        }
        __syncthreads();    // drains next-tile stage (issued pre-compute)
        cur ^= 1;
    }

    if (MODE == 1) {        // one sred reduction for all 4 tiles
        sred[t] = 0.0f;
        __syncthreads();
#pragma unroll
        for (int n = 0; n < 8; ++n) {
            const int c = n * 16 + lc;
            atomicAdd(&sred[c], ps[n]);
            atomicAdd(&sred[DD + c], ps2[n]);
        }
        __syncthreads();
        atomicAdd(&bnsums[t], sred[t]);
    }
}

// ---------------- CSR aggregate: LDS-broadcast edge stream (r13-proven) ------
__global__ __launch_bounds__(256) void k_aggregate(const int* __restrict__ rowp,
                                                   const float* __restrict__ dinv,
                                                   const int* __restrict__ ssrc,
                                                   const uint* __restrict__ hb,
                                                   uint* __restrict__ aggb) {
    __shared__ float2 eb[4][64];
    const int wv = threadIdx.x >> 6;
    const int n = blockIdx.x * 4 + wv;
    const int l = threadIdx.x & 63;
    const float dn = dinv[n];
    const uint u0 = hb[((uint)n << 6) + l];
    const float dn2 = dn * dn;
    float ax = dn2 * bflo(u0), ay = dn2 * bfhi(u0);
    const int e0 = rowp[n], e1 = rowp[n + 1];
    for (int base = e0; base < e1; base += 64) {
        const int cnt = min(64, e1 - base);
        float nm = 0.0f; uint sb = 0;
        if (l < cnt) {
            const uint p = (uint)__builtin_nontemporal_load(ssrc + base + l);
            sb = (p & 0x1FFFFu) << 6;
            nm = dn * rsqrtf((float)(p >> 17));   // = dn * dinv[src]
        }
        eb[wv][l] = make_float2(nm, __uint_as_float(sb));   // wave-private slot
        int i = 0;
        for (; i + 16 <= cnt; i += 16) {         // bulk: all-real, 16 in flight
            uint vv[16]; float nmv[16];
#pragma unroll
            for (int j = 0; j < 16; ++j) {
                const float2 e = eb[wv][i + j];  // broadcast read
                nmv[j] = e.x;
                vv[j] = hb[__float_as_uint(e.y) + l];
            }
#pragma unroll
            for (int j = 0; j < 16; ++j) {
                ax += nmv[j] * bflo(vv[j]);
                ay += nmv[j] * bfhi(vv[j]);
            }
        }
        for (; i < cnt; i += 8) {                // tail: padded (nm=0 lanes)
            uint vv[8]; float nmv[8];
#pragma unroll
            for (int j = 0; j < 8; ++j) {
                const float2 e = eb[wv][i + j];
                nmv[j] = e.x;
                vv[j] = hb[__float_as_uint(e.y) + l];
            }
#pragma unroll
            for (int j = 0; j < 8; ++j) {
                ax += nmv[j] * bflo(vv[j]);
                ay += nmv[j] * bfhi(vv[j]);
            }
        }
    }
    aggb[((uint)n << 6) + l] = (uint)f2bf(ax) | ((uint)f2bf(ay) << 16);
}

// ---------------- launch ----------------
extern "C" void kernel_launch(void* const* d_in, const int* in_sizes, int n_in,
                              void* d_out, int out_size, void* d_ws, size_t ws_size,
                              hipStream_t stream) {
    const float* x      = (const float*)d_in[0];
    const int*   ei     = (const int*)d_in[1];
    const float* W_init = (const float*)d_in[3];
    const float* W_gcn  = (const float*)d_in[4];
    const float* gamma  = (const float*)d_in[6];
    const float* beta   = (const float*)d_in[7];
    const float* W_res  = (const float*)d_in[8];
    const float* b_res  = (const float*)d_in[9];

    float* h = (float*)d_out;
    char* p = (char*)d_ws;
    ushort* aggb = (ushort*)p;           p += (size_t)NN * DD * 2;   // 32MB
    ushort* hb   = (ushort*)p;           p += (size_t)NN * DD * 2;   // 32MB
    ushort* convb = (ushort*)p;          p += (size_t)NN * DD * 2;   // 32MB
    uint*   xb   = (uint*)convb;         // aliases convb: dead before conv write
    float*  dinv = (float*)p;            p += (size_t)NN * 4;
    int*    deg  = (int*)p;              p += (size_t)NN * 4;
    float*  bns  = (float*)p;            p += 768 * 4;
    ushort* wt   = (ushort*)p;           p += 7 * 16384 * 2;
    int* blockHist = (int*)p;            p += (size_t)NB * NB * 4;
    int* rowSum  = (int*)p;              p += NB * 4;
    int* bstart  = (int*)p;              p += (NB + 1) * 4 + 4;
    uint* packed = (uint*)p;             p += (size_t)NE * 4;
    int* rowp    = (int*)p;              p += ((size_t)NN + 1) * 4 + 4;
    int* ssrc    = (int*)p;

    const int* srcp = ei;
    const int* tgtp = ei + NE;

    k_prep<<<NN * 64 / 256, 256, 0, stream>>>(x, W_init, W_gcn, W_res, xb, wt, bns);
    kA_count<<<NB, 256, 0, stream>>>(tgtp, blockHist);
    kA_scan1<<<NB, 256, 0, stream>>>(blockHist, rowSum);
    kA_scatter<<<NB, 256, 0, stream>>>(srcp, tgtp, blockHist, rowSum, bstart, packed);
    kB_sort<<<NB, 256, 0, stream>>>(packed, bstart, rowp, dinv, deg, ssrc);
    k_pack<<<NE / 256, 256, 0, stream>>>(ssrc, deg);

    k_mgemm<0><<<NN / 256, 256, 0, stream>>>((const ushort*)xb, wt, hb,
                                             nullptr, nullptr, nullptr, nullptr,
                                             nullptr, nullptr);

    for (int i = 0; i < LL; ++i) {
        k_aggregate<<<NN / 4, 256, 0, stream>>>(rowp, dinv, ssrc,
                                                (const uint*)hb, (uint*)aggb);
        k_mgemm<1><<<NN / 256, 256, 0, stream>>>(aggb, wt + (size_t)(1 + i) * 16384,
                                                 convb, nullptr, nullptr, nullptr,
                                                 nullptr, nullptr, bns + i * 256);
        if (i < LL - 1)
            k_mgemm<2><<<NN / 256, 256, 0, stream>>>(hb, wt + (size_t)(4 + i) * 16384,
                                                     hb, nullptr, convb,
                                                     gamma + i * DD, beta + i * DD,
                                                     b_res + i * DD, bns + i * 256);
        else
            k_mgemm<3><<<NN / 256, 256, 0, stream>>>(hb, wt + (size_t)(4 + i) * 16384,
                                                     nullptr, h, convb,
                                                     gamma + i * DD, beta + i * DD,
                                                     b_res + i * DD, bns + i * 256);
    }
}